// Round 1
// 704.771 us; speedup vs baseline: 1.0842x; 1.0842x over previous
//
#include <hip/hip_runtime.h>
#include <cstdint>
#include <type_traits>

typedef unsigned short u16;
typedef __attribute__((ext_vector_type(8))) short short8;
typedef __attribute__((ext_vector_type(4))) float f32x4;

__device__ __forceinline__ u16 f2bf(float f) {
  unsigned x;
  __builtin_memcpy(&x, &f, 4);
  x = x + 0x7fffu + ((x >> 16) & 1u);  // RNE
  return (u16)(x >> 16);
}
__device__ __forceinline__ f32x4 mfma16(short8 a, short8 b, f32x4 c) {
  return __builtin_amdgcn_mfma_f32_16x16x32_bf16(a, b, c, 0, 0, 0);
}
__device__ __forceinline__ void async_cp16(const u16* g, const u16* l) {
  __builtin_amdgcn_global_load_lds(
      (const __attribute__((address_space(1))) unsigned int*)(uintptr_t)g,
      (__attribute__((address_space(3))) unsigned int*)(uintptr_t)l, 16, 0, 0);
}

// ---------------------------------------------------------------------------
// fp32 -> bf16 conversion (vectorized: float4 in, ushort4 out)
// ---------------------------------------------------------------------------
__global__ __launch_bounds__(256)
void cvt_f32_bf16(const float* __restrict__ s, u16* __restrict__ d, long n4) {
  long i = (long)blockIdx.x * 256 + threadIdx.x;
  if (i < n4) {
    float4 f = ((const float4*)s)[i];
    ushort4 o;
    o.x = f2bf(f.x);
    o.y = f2bf(f.y);
    o.z = f2bf(f.z);
    o.w = f2bf(f.w);
    ((ushort4*)d)[i] = o;
  }
}

// zero-fill (short8 stores); used to clear vtg pads before the V^T writes
__global__ __launch_bounds__(256)
void zero16(u16* __restrict__ p, long n8) {
  long i = (long)blockIdx.x * 256 + threadIdx.x;
  if (i < n8) {
    short8 z = {0, 0, 0, 0, 0, 0, 0, 0};
    ((short8*)p)[i] = z;
  }
}

// ---------------------------------------------------------------------------
// Weight transpose + cast: W fp32 (1024x1024, row-major K,N) -> WT bf16 (N,K)
// ---------------------------------------------------------------------------
struct TP { const float* s[6]; u16* d[6]; };

__global__ __launch_bounds__(256)
void transpose6(TP a) {
  __shared__ float tile[32][33];
  const float* S = a.s[blockIdx.z];
  u16* D = a.d[blockIdx.z];
  const int tx = threadIdx.x, ty = threadIdx.y;
  const int bx = blockIdx.x * 32, by = blockIdx.y * 32;
#pragma unroll
  for (int i = 0; i < 32; i += 8)
    tile[ty + i][tx] = S[(long)(by + ty + i) * 1024 + bx + tx];
  __syncthreads();
#pragma unroll
  for (int i = 0; i < 32; i += 8)
    D[(long)(bx + ty + i) * 1024 + by + tx] = f2bf(tile[tx][ty + i]);
}

// ---------------------------------------------------------------------------
// GEMM C = A * B  (m97 structure: 128x128 tile, BK=32, global_load_lds w=16).
// Row map: (m/RPB)*BSTR + m%RPB + ROFF on A reads and (normal) C writes.
// grid.z selects (Bt0->C0)/(Bt1->C1). When VT is set, z==1 writes C^T into a
// [b][n=1024][384] bf16 layout at column vtcol + m%RPB (V^T for attention).
// ---------------------------------------------------------------------------
template <typename CT, bool VT>
__global__ __launch_bounds__(256, 2)
void gemm_bt(const u16* __restrict__ A, const u16* __restrict__ Bt0,
             const u16* __restrict__ Bt1, CT* __restrict__ C0,
             CT* __restrict__ C1, const float* __restrict__ bias,
             int M, int RPB, int BSTR, int ROFF, int vtcol) {
  const u16* Bt = (blockIdx.z == 0) ? Bt0 : Bt1;
  CT* C = (blockIdx.z == 0) ? C0 : C1;
  __shared__ u16 As[128 * 32];
  __shared__ u16 Bs[128 * 32];
  const int t = threadIdx.x;
  const int w = t >> 6, lane = t & 63;
  const int m0 = blockIdx.x * 128, n0 = blockIdx.y * 128;
  const int subk = (lane & 3) * 8;

  long ag[2], bg[2];
  int lo[2];
#pragma unroll
  for (int r = 0; r < 2; ++r) {
    int m = m0 + r * 64 + w * 16 + (lane >> 2);
    if (m >= M) m = M - 1;  // clamp: duplicate loads, stores guarded below
    long row = (long)(m / RPB) * BSTR + (m % RPB) + ROFF;
    ag[r] = row * 1024 + subk;
    lo[r] = r * 2048 + w * 512 + (lane >> 2) * 32 + subk;  // == base + 8*lane
    int n = n0 + r * 64 + w * 16 + (lane >> 2);
    bg[r] = (long)n * 1024 + subk;
  }
  const int wm = w >> 1, wn = w & 1;
  const int lr = lane & 15, quad = lane >> 4;
  const u16* Ap = As + (wm * 64 + lr) * 32 + quad * 8;
  const u16* Bp = Bs + (wn * 64 + lr) * 32 + quad * 8;

  const f32x4 fz = {0.f, 0.f, 0.f, 0.f};
  f32x4 acc[4][4];
#pragma unroll
  for (int i = 0; i < 4; ++i)
#pragma unroll
    for (int j = 0; j < 4; ++j) acc[i][j] = fz;

  for (int k0 = 0; k0 < 1024; k0 += 32) {
    __syncthreads();
    async_cp16(A + ag[0] + k0, As + lo[0]);
    async_cp16(A + ag[1] + k0, As + lo[1]);
    async_cp16(Bt + bg[0] + k0, Bs + lo[0]);
    async_cp16(Bt + bg[1] + k0, Bs + lo[1]);
    __syncthreads();  // drains vmcnt before barrier
    short8 a[4], b[4];
#pragma unroll
    for (int i = 0; i < 4; ++i) a[i] = *(const short8*)(Ap + i * 512);
#pragma unroll
    for (int i = 0; i < 4; ++i) b[i] = *(const short8*)(Bp + i * 512);
#pragma unroll
    for (int i = 0; i < 4; ++i)
#pragma unroll
      for (int j = 0; j < 4; ++j) acc[i][j] = mfma16(a[i], b[j], acc[i][j]);
  }

  // C/D layout: row = quad*4 + reg, col = lane&15 (measured m89/m91)
  if constexpr (VT) {
    if (blockIdx.z == 1) {  // V: write transposed into vtg [b][n][384]
#pragma unroll
      for (int i = 0; i < 4; ++i)
#pragma unroll
        for (int r = 0; r < 4; ++r) {
          int m = m0 + wm * 64 + i * 16 + quad * 4 + r;
          if (m < M) {
            long vrow = (long)(m / RPB) * 1024;
            int j = m % RPB;
#pragma unroll
            for (int jj = 0; jj < 4; ++jj) {
              int n = n0 + wn * 64 + jj * 16 + lr;
              C[(vrow + n) * 384 + vtcol + j] = (CT)f2bf(acc[i][jj][r]);
            }
          }
        }
      return;
    }
  }
#pragma unroll
  for (int i = 0; i < 4; ++i) {
#pragma unroll
    for (int r = 0; r < 4; ++r) {
      int m = m0 + wm * 64 + i * 16 + quad * 4 + r;
      if (m < M) {
        long crow = ((long)(m / RPB) * BSTR + (m % RPB) + ROFF) * 1024;
#pragma unroll
        for (int j = 0; j < 4; ++j) {
          int n = n0 + wn * 64 + j * 16 + lr;
          float v = acc[i][j][r];
          if (bias) v += bias[n];
          if constexpr (std::is_same<CT, float>::value)
            C[crow + n] = v;
          else
            C[crow + n] = f2bf(v);
        }
      }
    }
  }
}

// ---------------------------------------------------------------------------
// Attention: one WG = (b, h, 64-row q tile), 4 waves x 16 rows each.
// 3 key chunks: txt [0,77)->96 (standalone softmax), img [77,205) + [205,333)
// (online softmax into a separate accumulator, merged at the end).
// V^T is staged from the pre-transposed global vtg via global_load_lds with a
// T2 XOR swizzle (linear LDS dest, inverse-swizzled per-lane global source;
// swizzle re-applied on ds_read). Vt stride 128, Pb stride 136 -> 33.8 KB LDS
// -> 4 blocks/CU (was 2).
// ---------------------------------------------------------------------------
__device__ __forceinline__ void stage_vt(const u16* __restrict__ vrow,
                                         int colbase, u16* Vt, int t) {
#pragma unroll
  for (int it = 0; it < 4; ++it) {
    int G = it * 256 + t;       // 16B group in LDS (linear dest)
    int r = G >> 4, p = G & 15; // row, phys group
    int g = p ^ (r & 7);        // logical column group (inverse == forward)
    async_cp16(vrow + (long)r * 384 + colbase + g * 8, Vt + G * 8);
  }
}

template <int JT>
__device__ __forceinline__ void qk_mm(const u16* __restrict__ kbase, short8 aq0,
                                      short8 aq1, int lr, int quad,
                                      f32x4* sacc) {
#pragma unroll
  for (int jt = 0; jt < JT; ++jt) {
    const u16* kp = kbase + (long)(jt * 16 + lr) * 1024 + quad * 8;
    short8 b0 = *(const short8*)kp;
    short8 b1 = *(const short8*)(kp + 32);
    f32x4 z = {0.f, 0.f, 0.f, 0.f};
    z = mfma16(aq0, b0, z);
    sacc[jt] = mfma16(aq1, b1, z);
  }
}

template <int JT>
__device__ __forceinline__ void pv_mm(const u16* Vt, const u16* Pb, int w,
                                      int lr, int quad, f32x4* oacc) {
#pragma unroll
  for (int c = 0; c < JT / 2; ++c) {
    short8 pf = *(const short8*)(Pb + (w * 16 + lr) * 136 + c * 32 + quad * 8);
#pragma unroll
    for (int nt = 0; nt < 4; ++nt) {
      int g = (c * 4 + quad) ^ (lr & 7);  // row&7 == lr&7 for row=nt*16+lr
      short8 vf = *(const short8*)(Vt + (nt * 16 + lr) * 128 + g * 8);
      oacc[nt] = mfma16(pf, vf, oacc[nt]);
    }
  }
}

__device__ __forceinline__ void img_chunk(int koff, int colbase,
                                          const u16* __restrict__ kbh,
                                          const u16* __restrict__ vbh, u16* Vt,
                                          u16* Pb, short8 aq0, short8 aq1,
                                          f32x4 (&oi)[4], float (&mrun)[4],
                                          float (&lrun)[4], int t, int w,
                                          int lr, int quad) {
  __syncthreads();  // previous chunk's PV done reading Vt
  stage_vt(vbh, colbase, Vt, t);  // async; hides under QK + softmax
  f32x4 sacc[8];
  qk_mm<8>(kbh + (long)koff * 1024, aq0, aq1, lr, quad, sacc);
#pragma unroll
  for (int r = 0; r < 4; ++r) {
    float mprev = mrun[r];
    float mx = mprev;
#pragma unroll
    for (int jt = 0; jt < 8; ++jt) {
      float v = sacc[jt][r] * 0.125f;  // SCALE = 1/8
      sacc[jt][r] = v;
      mx = fmaxf(mx, v);
    }
#pragma unroll
    for (int d = 1; d < 16; d <<= 1) mx = fmaxf(mx, __shfl_xor(mx, d, 64));
    float sc = __expf(mprev - mx);  // first chunk: exp(-inf) = 0
    int row = w * 16 + quad * 4 + r;
    float s = 0.f;
#pragma unroll
    for (int jt = 0; jt < 8; ++jt) {
      float p = __expf(sacc[jt][r] - mx);
      s += p;
      Pb[row * 136 + jt * 16 + lr] = f2bf(p);  // unnormalized, <= 1
    }
#pragma unroll
    for (int d = 1; d < 16; d <<= 1) s += __shfl_xor(s, d, 64);
    lrun[r] = lrun[r] * sc + s;
    mrun[r] = mx;
#pragma unroll
    for (int nt = 0; nt < 4; ++nt) oi[nt][r] *= sc;
  }
  __syncthreads();  // Vt staged (vmcnt drained by barrier)
  pv_mm<8>(Vt, Pb, w, lr, quad, oi);
}

__global__ __launch_bounds__(256, 4)
void attn_kernel(u16* __restrict__ q, const u16* __restrict__ kall,
                 const u16* __restrict__ vtg) {
  __shared__ u16 Vt[64 * 128];  // V^T chunk, XOR-swizzled 16B groups
  __shared__ u16 Pb[64 * 136];  // P, stride 136 (17 dw-quads: conflict-min)
  const int t = threadIdx.x;
  const int w = t >> 6, lane = t & 63;
  const int lr = lane & 15, quad = lane >> 4;
  const int bq = blockIdx.x, h = blockIdx.y, b = blockIdx.z;
  const long qrow = (long)(b * 2048 + bq * 64 + w * 16 + lr) * 1024 + h * 64;
  short8 aq0 = *(const short8*)(q + qrow + quad * 8);
  short8 aq1 = *(const short8*)(q + qrow + 32 + quad * 8);
  const f32x4 fz = {0.f, 0.f, 0.f, 0.f};
  f32x4 ot[4], oi[4];
#pragma unroll
  for (int i = 0; i < 4; ++i) { ot[i] = fz; oi[i] = fz; }
  float mrun[4], lrun[4];
#pragma unroll
  for (int r = 0; r < 4; ++r) { mrun[r] = -3.0e38f; lrun[r] = 0.f; }
  const u16* kbh = kall + (long)b * 333 * 1024 + h * 64;
  const u16* vbh = vtg + (long)(b * 16 + h) * 64 * 384;

  // ---- chunk 0: txt keys [0,77) padded to 96, standalone softmax -> ot ----
  stage_vt(vbh, 0, Vt, t);
  {
    f32x4 sacc[6];
    qk_mm<6>(kbh, aq0, aq1, lr, quad, sacc);
#pragma unroll
    for (int r = 0; r < 4; ++r) {
      float mx = -3.0e38f;
#pragma unroll
      for (int jt = 0; jt < 6; ++jt) {
        int j = jt * 16 + lr;
        float v = (j < 77) ? sacc[jt][r] * 0.125f : -3.0e38f;
        sacc[jt][r] = v;
        mx = fmaxf(mx, v);
      }
#pragma unroll
      for (int d = 1; d < 16; d <<= 1) mx = fmaxf(mx, __shfl_xor(mx, d, 64));
      float s = 0.f;
#pragma unroll
      for (int jt = 0; jt < 6; ++jt) {
        float p = __expf(sacc[jt][r] - mx);  // masked -> 0 exactly
        sacc[jt][r] = p;
        s += p;
      }
#pragma unroll
      for (int d = 1; d < 16; d <<= 1) s += __shfl_xor(s, d, 64);
      float is = 1.0f / s;
      int row = w * 16 + quad * 4 + r;
#pragma unroll
      for (int jt = 0; jt < 6; ++jt)
        Pb[row * 136 + jt * 16 + lr] = f2bf(sacc[jt][r] * is);
    }
    __syncthreads();  // Vt staged
    pv_mm<6>(Vt, Pb, w, lr, quad, ot);  // pad cols 77..95 of vtg are zero
  }
  // ---- chunks 1,2: img keys [77,205), [205,333), online softmax -> oi ----
  img_chunk(77, 96, kbh, vbh, Vt, Pb, aq0, aq1, oi, mrun, lrun, t, w, lr, quad);
  img_chunk(205, 224, kbh, vbh, Vt, Pb, aq0, aq1, oi, mrun, lrun, t, w, lr, quad);

  // IMG_SCALE = 1.0; out = ot + oi/l. Overwrite q in place.
#pragma unroll
  for (int r = 0; r < 4; ++r) {
    float il = 1.0f / lrun[r];
    long row = (long)(b * 2048 + bq * 64 + w * 16 + quad * 4 + r);
#pragma unroll
    for (int nt = 0; nt < 4; ++nt)
      q[row * 1024 + h * 64 + nt * 16 + lr] = f2bf(ot[nt][r] + oi[nt][r] * il);
  }
}

// ---------------------------------------------------------------------------
extern "C" void kernel_launch(void* const* d_in, const int* in_sizes, int n_in,
                              void* d_out, int out_size, void* d_ws,
                              size_t ws_size, hipStream_t stream) {
  const float* x = (const float*)d_in[0];    // (16, 2048, 1024) fp32
  const float* ctx = (const float*)d_in[1];  // (16, 333, 1024) fp32
  u16* ws = (u16*)d_ws;
  // ws layout (u16 elems):
  //   WT[6]  : 6 x 1M        (transposed bf16 weights)
  //   xb     : 32M           (x as bf16; DEAD after q GEMM -> vtg aliases it)
  //   qb     : 32M           (q, then attention output, bf16)
  //   ctxb   : 16*333*1024   (context as bf16)
  //   kall   : 16*333*1024   (k for both segments, bf16)
  //   vtg    : 16*1024*384   (V^T: [b][n][384], txt@0..76, img@96..351)
  u16* WT[6];
  for (int i = 0; i < 6; ++i) WT[i] = ws + (size_t)i * (1u << 20);
  u16* xb = ws + (size_t)6 * (1u << 20);
  u16* qb = xb + (size_t)(1u << 25);
  u16* ctxb = qb + (size_t)(1u << 25);
  u16* kall = ctxb + (size_t)16 * 333 * 1024;
  u16* vtg = xb;  // alias: x is consumed by the q GEMM before vtg is written
  float* out = (float*)d_out;

  // fp32 -> bf16 for activations
  cvt_f32_bf16<<<dim3(32768), dim3(256), 0, stream>>>(x, xb, 8388608);
  cvt_f32_bf16<<<dim3(5328), dim3(256), 0, stream>>>(ctx, ctxb, 1363968);

  TP tp;
  tp.s[0] = (const float*)d_in[2]; tp.d[0] = WT[0];  // Wq
  tp.s[1] = (const float*)d_in[3]; tp.d[1] = WT[1];  // Wk
  tp.s[2] = (const float*)d_in[4]; tp.d[2] = WT[2];  // Wv
  tp.s[3] = (const float*)d_in[5]; tp.d[3] = WT[3];  // Wk_ip
  tp.s[4] = (const float*)d_in[6]; tp.d[4] = WT[4];  // Wv_ip
  tp.s[5] = (const float*)d_in[7]; tp.d[5] = WT[5];  // Wo
  transpose6<<<dim3(32, 32, 6), dim3(32, 8, 1), 0, stream>>>(tp);

  // q = x @ Wq : M=32768 rows contiguous (reads xb -- must precede zero16)
  gemm_bt<u16, false><<<dim3(256, 8, 1), dim3(256), 0, stream>>>(
      xb, WT[0], WT[0], qb, qb, (const float*)nullptr, 32768, 2048, 2048, 0, -1);
  // clear vtg (zeroes the pad cols 77..95 / 352..383 the GEMMs don't write)
  zero16<<<dim3(3072), dim3(256), 0, stream>>>(vtg, 786432);
  // k/v txt: M=16*77; z=0 writes K rows (m/77)*333+m%77; z=1 writes V^T @col 0
  gemm_bt<u16, true><<<dim3(10, 8, 2), dim3(256), 0, stream>>>(
      ctxb, WT[1], WT[2], kall, vtg, (const float*)nullptr, 1232, 77, 333, 0, 0);
  // k/v img: M=16*256; z=0 writes K rows +77; z=1 writes V^T @col 96
  gemm_bt<u16, true><<<dim3(32, 8, 2), dim3(256), 0, stream>>>(
      ctxb, WT[3], WT[4], kall, vtg, (const float*)nullptr, 4096, 256, 333, 77, 96);
  // attention (overwrites qb with concat-head outputs)
  attn_kernel<<<dim3(32, 16, 16), dim3(256), 0, stream>>>(qb, kall, vtg);
  // out = attn @ Wo + bo  (fp32 out, fp32 bias)
  gemm_bt<float, false><<<dim3(256, 8, 1), dim3(256), 0, stream>>>(
      qb, WT[5], WT[5], out, out, (const float*)d_in[8], 32768, 2048, 2048, 0, -1);
}